// Round 6
// baseline (305.174 us; speedup 1.0000x reference)
//
#include <hip/hip_runtime.h>

#define CIN    128
#define HH     56
#define WW_    56
#define NBATCH 32
#define COUT   256
#define KTOT   1152          // 9 taps * 128 ci  (k-order: kh, kw, ci)
#define PLANE  3136          // 56*56
#define HP     58            // padded H/W
#define BM     128           // c_out tile
#define BN     128           // pixel tile
#define BK     64            // k per staging step (18 steps total)

#define WB_OFF   0                         // bf16 weights [256][9][128] in ws
#define XP_OFF   (1u << 20)                // padded bf16 input [32][58][58][128]
#define LSTR     66                        // prep LDS stride (shorts)

typedef __attribute__((ext_vector_type(8))) short bf16x8;
typedef __attribute__((ext_vector_type(4))) float f32x4;

__device__ __forceinline__ unsigned short f2bf(float f) {
    unsigned int u = __builtin_bit_cast(unsigned int, f);
    u += 0x7fffu + ((u >> 16) & 1u);   // RNE
    return (unsigned short)(u >> 16);
}

__device__ __forceinline__ void gl_lds16(const void* g, void* l) {
    __builtin_amdgcn_global_load_lds(
        (const __attribute__((address_space(1))) void*)g,
        (__attribute__((address_space(3))) void*)l, 16, 0, 0);
}

// ---- fused prep: blocks [0,1856) = input NCHW->padded NHWC bf16; [1856,1888) = weights ----
__global__ __launch_bounds__(256)
void prep(const float* __restrict__ in, const float* __restrict__ wt,
          unsigned short* __restrict__ xp, unsigned short* __restrict__ wb) {
    const int b = blockIdx.x;
    const int t = threadIdx.x;

    if (b >= NBATCH * HP) {               // weight conversion: 8 c_out rows per block
        const int o0 = (b - NBATCH * HP) * 8;
        for (int oo = 0; oo < 8; ++oo) {
            const float* src = wt + (size_t)(o0 + oo) * KTOT;
            unsigned short* dst = wb + (size_t)(o0 + oo) * KTOT;
            #pragma unroll
            for (int e = 0; e < 5; ++e) {
                const int idx = t + e * 256;       // = ci*9 + tap
                if (idx < KTOT) {
                    const int ci  = idx / 9;
                    const int tap = idx - ci * 9;
                    dst[tap * 128 + ci] = f2bf(src[idx]);
                }
            }
        }
        return;
    }

    const int n  = b / HP;
    const int ho = b - n * HP;
    uint4* orow = (uint4*)(xp + (((size_t)n * HP + ho) * HP) * CIN);  // 928 uint4/row

    if (ho == 0 || ho == HP - 1) {        // border rows: pure zeros
        #pragma unroll
        for (int e = 0; e < 4; ++e) {
            const int idx = t + e * 256;
            if (idx < 928) orow[idx] = (uint4){0u, 0u, 0u, 0u};
        }
        return;
    }

    __shared__ unsigned short L[CIN * LSTR];
    const int h  = ho - 1;
    const int f4 = t & 15;                // float4 slot within row (0..13 valid)
    const int cg = t >> 4;                // ci group 0..15
    if (f4 < 14) {
        const float* rowb = in + ((size_t)n * CIN) * PLANE + (size_t)h * WW_;
        #pragma unroll
        for (int g = 0; g < 8; ++g) {
            const int ci = cg + g * 16;
            const float4 v = *(const float4*)(rowb + (size_t)ci * PLANE + f4 * 4);
            unsigned lo = (unsigned)f2bf(v.x) | ((unsigned)f2bf(v.y) << 16);
            unsigned hi = (unsigned)f2bf(v.z) | ((unsigned)f2bf(v.w) << 16);
            *(unsigned*)&L[ci * LSTR + f4 * 4]     = lo;
            *(unsigned*)&L[ci * LSTR + f4 * 4 + 2] = hi;
        }
    }
    __syncthreads();

    #pragma unroll
    for (int e = 0; e < 4; ++e) {
        const int idx = t + e * 256;      // uint4 index in padded output row
        if (idx < 928) {
            const int wo = idx >> 4;      // pixel 0..57
            const int ch = idx & 15;      // 8-ci chunk
            uint4 pk = {0u, 0u, 0u, 0u};
            if (wo >= 1 && wo <= WW_) {
                const int wi = wo - 1;
                unsigned v[8];
                #pragma unroll
                for (int i = 0; i < 8; ++i)
                    v[i] = L[(ch * 8 + i) * LSTR + wi];
                pk.x = v[0] | (v[1] << 16);
                pk.y = v[2] | (v[3] << 16);
                pk.z = v[4] | (v[5] << 16);
                pk.w = v[6] | (v[7] << 16);
            }
            orow[idx] = pk;
        }
    }
}

// ---- main conv: A (weights) double-buffered in LDS via DMA; B direct global->reg ----
__global__ __launch_bounds__(256, 2)
void conv_mfma(const unsigned short* __restrict__ wb,
               const unsigned short* __restrict__ xp,
               const float* __restrict__ bias,
               float* __restrict__ out)
{
    __shared__ __align__(16) unsigned short Asm_[2 * BM * BK];  // 2 x 16 KB

    const int t   = threadIdx.x;
    // XCD-band swizzle: consecutive blocks round-robin XCDs; give each XCD a
    // contiguous band of pixel tiles with the c-pair adjacent.
    const int g    = (blockIdx.x & 7) * 196 + (blockIdx.x >> 3);
    const int pix0 = (g >> 1) * BN;
    const int c0   = (g & 1) * BM;

    // A staging: thread t fetches logical 16B chunk (slot^swz(r32)) of row r32+p*32
    const int slot = t & 7;
    const int r32  = t >> 3;
    const int swiz = (slot ^ (r32 & 7)) * 16;
    const char* aBase = (const char*)wb + (size_t)(c0 + r32) * (KTOT * 2) + swiz;

    // compute coords
    const int lane = t & 63;
    const int wave = t >> 6;
    const int wm   = (wave & 1) * 64;
    const int wn   = (wave >> 1) * 64;
    const int lr   = lane & 15;
    const int quad = lane >> 4;
    const int rmod = lr & 7;

    // B pixel row bases (per j)
    const char* pixB[4];
    #pragma unroll
    for (int j = 0; j < 4; ++j) {
        const int pix = pix0 + wn + j * 16 + lr;
        const int n   = pix / PLANE;
        const int rem = pix - n * PLANE;
        const int h   = rem / WW_;
        const int w   = rem - h * WW_;
        pixB[j] = (const char*)xp + ((size_t)(n * HP + h) * HP + w) * (CIN * 2) + quad * 16;
    }

    char* const asmb = (char*)Asm_;

    f32x4 acc[4][4];
    #pragma unroll
    for (int i = 0; i < 4; ++i)
        #pragma unroll
        for (int j = 0; j < 4; ++j)
            acc[i][j] = (f32x4){0.f, 0.f, 0.f, 0.f};

    // helpers (s: 0..17; tap = s>>1, ci-half = s&1)
    auto stageA = [&](int s, int bufOff) {
        const int abyte = (s >> 1) * 256 + (s & 1) * 128;
        #pragma unroll
        for (int p = 0; p < 4; ++p)
            gl_lds16(aBase + (size_t)p * 32 * (KTOT * 2) + abyte,
                     asmb + bufOff + p * 4096 + t * 16);
    };
    auto loadB = [&](int s, bf16x8 (&dst)[2][4]) {
        const int tap  = s >> 1;
        const int boff = ((tap / 3) * HP + (tap % 3)) * (CIN * 2) + (s & 1) * 128;
        #pragma unroll
        for (int kk = 0; kk < 2; ++kk)
            #pragma unroll
            for (int j = 0; j < 4; ++j)
                dst[kk][j] = *(const bf16x8*)(pixB[j] + boff + kk * 64);
    };
    auto compute = [&](int bufOff, const bf16x8 (&bc)[2][4]) {
        #pragma unroll
        for (int kk = 0; kk < 2; ++kk) {
            bf16x8 af[4];
            #pragma unroll
            for (int i = 0; i < 4; ++i)
                af[i] = *(const bf16x8*)(asmb + bufOff + (wm + i * 16 + lr) * 128
                                         + (((kk * 4 + quad) ^ rmod) * 16));
            #pragma unroll
            for (int i = 0; i < 4; ++i)
                #pragma unroll
                for (int j = 0; j < 4; ++j)
                    acc[i][j] = __builtin_amdgcn_mfma_f32_16x16x32_bf16(af[i], bc[kk][j], acc[i][j], 0, 0, 0);
        }
    };

    bf16x8 bX[2][4], bY[2][4];
    stageA(0, 0);
    loadB(0, bX);
    __syncthreads();

    for (int s = 0; s < 18; s += 2) {
        // even step s: compute buf0/bX, prefetch s+1 -> buf1/bY
        stageA(s + 1, 16384);
        loadB(s + 1, bY);
        compute(0, bX);
        __syncthreads();
        // odd step s+1: compute buf1/bY, prefetch s+2 -> buf0/bX
        if (s + 2 < 18) {
            stageA(s + 2, 0);
            loadB(s + 2, bX);
        }
        compute(16384, bY);
        __syncthreads();
    }

    // epilogue: D[row=c_out][col=pix]; lane: col=lr, rows quad*4+r
    #pragma unroll
    for (int j = 0; j < 4; ++j) {
        const int pg    = pix0 + wn + j * 16 + lr;
        const int ni    = pg / PLANE;
        const int inner = pg - ni * PLANE;
        float* op = out + (size_t)ni * (COUT * PLANE) + inner;
        #pragma unroll
        for (int i = 0; i < 4; ++i) {
            const int crow = c0 + wm + i * 16 + quad * 4;
            #pragma unroll
            for (int r = 0; r < 4; ++r)
                op[(size_t)(crow + r) * PLANE] = acc[i][j][r] + bias[crow + r];
        }
    }
}

extern "C" void kernel_launch(void* const* d_in, const int* in_sizes, int n_in,
                              void* d_out, int out_size, void* d_ws, size_t ws_size,
                              hipStream_t stream) {
    const float* in   = (const float*)d_in[0];
    const float* wt   = (const float*)d_in[1];
    const float* bias = (const float*)d_in[2];
    float* out        = (float*)d_out;

    unsigned short* wb = (unsigned short*)((char*)d_ws + WB_OFF);
    unsigned short* xp = (unsigned short*)((char*)d_ws + XP_OFF);

    prep<<<NBATCH * HP + 32, 256, 0, stream>>>(in, wt, xp, wb);

    conv_mfma<<<(COUT / BM) * ((NBATCH * PLANE) / BN), 256, 0, stream>>>(wb, xp, bias, out);
}

// Round 7
// 232.329 us; speedup vs baseline: 1.3135x; 1.3135x over previous
//
#include <hip/hip_runtime.h>

#define CIN    128
#define HH     56
#define WW_    56
#define NBATCH 32
#define COUT   256
#define KTOT   1152          // 9 taps * 128 ci  (k-order: kh, kw, ci)
#define PLANE  3136          // 56*56
#define HP     58            // padded H/W
#define BM     128           // c_out tile
#define BN     128           // pixel tile
#define BK     64            // k per staging step

#define WB_OFF   0                         // bf16 weights [256][9][128] in ws
#define XP_OFF   (1u << 20)                // padded bf16 input [32][58][58][128]

typedef __attribute__((ext_vector_type(8))) short bf16x8;
typedef __attribute__((ext_vector_type(4))) float f32x4;

__device__ __forceinline__ unsigned short f2bf(float f) {
    unsigned int u = __builtin_bit_cast(unsigned int, f);
    u += 0x7fffu + ((u >> 16) & 1u);   // RNE
    return (unsigned short)(u >> 16);
}

__device__ __forceinline__ void gl_lds16(const void* g, void* l) {
    __builtin_amdgcn_global_load_lds(
        (const __attribute__((address_space(1))) void*)g,
        (__attribute__((address_space(3))) void*)l, 16, 0, 0);
}

// ---- pre-pass 1: weights OIHW fp32 -> [o][tap][ci] bf16; contiguous coalesced reads ----
__global__ void wprep(const float* __restrict__ w, unsigned short* __restrict__ wb) {
    const int o = blockIdx.x;
    const int t = threadIdx.x;
    const float* src = w + (size_t)o * KTOT;
    unsigned short* dst = wb + (size_t)o * KTOT;
    #pragma unroll
    for (int e = 0; e < 5; ++e) {
        const int idx = t + e * 256;          // = ci*9 + tap
        if (idx < KTOT) {
            const int ci  = idx / 9;
            const int tap = idx - ci * 9;
            dst[tap * 128 + ci] = f2bf(src[idx]);
        }
    }
}

// ---- pre-pass 2: NCHW fp32 -> padded NHWC bf16, borders written here (no memset) ----
__global__ __launch_bounds__(256)
void xprep(const float* __restrict__ in, unsigned short* __restrict__ xp) {
    const int b  = blockIdx.x;               // n*58 + h_out
    const int n  = b / HP;
    const int ho = b - n * HP;
    const int t  = threadIdx.x;
    uint4* orow = (uint4*)(xp + (((size_t)n * HP + ho) * HP) * CIN);  // 928 uint4 per row

    if (ho == 0 || ho == HP - 1) {
        #pragma unroll
        for (int e = 0; e < 4; ++e) {
            const int idx = t + e * 256;
            if (idx < 928) orow[idx] = (uint4){0u, 0u, 0u, 0u};
        }
        return;
    }

    __shared__ unsigned short L[CIN * 57];   // [ci][w], stride 57
    const int h  = ho - 1;
    const int w  = t & 63;
    const int cb = t >> 6;                   // wave id 0..3 -> ci block
    if (w < WW_) {
        const float* ib = in + ((size_t)n * CIN) * PLANE + (size_t)h * WW_ + w;
        #pragma unroll
        for (int e = 0; e < 32; ++e) {
            const int ci = cb * 32 + e;
            L[ci * 57 + w] = f2bf(ib[(size_t)ci * PLANE]);
        }
    }
    __syncthreads();

    #pragma unroll
    for (int e = 0; e < 4; ++e) {
        const int idx = t + e * 256;         // uint4 index within the row
        if (idx < 928) {
            const int wo = idx >> 4;         // pixel 0..57
            const int ch = idx & 15;         // 8-ci chunk
            uint4 pk = {0u, 0u, 0u, 0u};
            if (wo >= 1 && wo <= WW_) {
                const int wi = wo - 1;
                unsigned v[8];
                #pragma unroll
                for (int i = 0; i < 8; ++i)
                    v[i] = L[(ch * 8 + i) * 57 + wi];
                pk.x = v[0] | (v[1] << 16);
                pk.y = v[2] | (v[3] << 16);
                pk.z = v[4] | (v[5] << 16);
                pk.w = v[6] | (v[7] << 16);
            }
            orow[idx] = pk;
        }
    }
}

// ---- main: implicit-GEMM conv (R3 structure), XCD-band swizzle, occupancy 4 ----
__global__ __launch_bounds__(256, 4)
void conv_mfma(const unsigned short* __restrict__ wb,
               const unsigned short* __restrict__ xp,
               const float* __restrict__ bias,
               float* __restrict__ out)
{
    __shared__ __align__(16) unsigned short Asm_[BM * BK];  // 16 KB
    __shared__ __align__(16) unsigned short Bsm_[BN * BK];  // 16 KB

    const int t = threadIdx.x;
    // XCD-band swizzle: blockIdx round-robins XCDs; give each XCD a contiguous
    // band of 98 pixel-tiles (3.4 MB xp slice fits its 4 MB L2), c-pair adjacent.
    const int g    = (blockIdx.x & 7) * 196 + (blockIdx.x >> 3);
    const int pix0 = (g >> 1) * BN;
    const int c0   = (g & 1) * BM;

    const int slot = t & 7;
    const int r32  = t >> 3;                 // 0..31
    const int swiz = (slot ^ (r32 & 7)) * 16;

    const char* aBase = (const char*)wb + (size_t)(c0 + r32) * (KTOT * 2) + swiz;
    const char* bBase[4];
    #pragma unroll
    for (int p = 0; p < 4; ++p) {
        const int pix = pix0 + r32 + p * 32;
        const int n   = pix / PLANE;
        const int rem = pix - n * PLANE;
        const int h   = rem / WW_;
        const int w   = rem - h * WW_;
        bBase[p] = (const char*)xp + ((size_t)(n * HP + h) * HP + w) * (CIN * 2) + swiz;
    }

    const int lane = t & 63;
    const int wave = t >> 6;
    const int wm   = (wave & 1) * 64;
    const int wn   = (wave >> 1) * 64;
    const int lr   = lane & 15;
    const int quad = lane >> 4;
    const int rmod = lr & 7;

    f32x4 acc[4][4];
    #pragma unroll
    for (int i = 0; i < 4; ++i)
        #pragma unroll
        for (int j = 0; j < 4; ++j)
            acc[i][j] = (f32x4){0.f, 0.f, 0.f, 0.f};

    char* const asmb = (char*)Asm_;
    char* const bsmb = (char*)Bsm_;

    for (int tap = 0; tap < 9; ++tap) {
        const int toff = ((tap / 3) * HP + (tap % 3)) * (CIN * 2);
        for (int ci0b = 0; ci0b < 256; ci0b += 128) {
            const int abyte = tap * 256 + ci0b;
            #pragma unroll
            for (int p = 0; p < 4; ++p)
                gl_lds16(aBase + (size_t)p * 32 * (KTOT * 2) + abyte, asmb + p * 4096 + t * 16);
            #pragma unroll
            for (int p = 0; p < 4; ++p)
                gl_lds16(bBase[p] + toff + ci0b, bsmb + p * 4096 + t * 16);
            __syncthreads();

            #pragma unroll
            for (int kk = 0; kk < 2; ++kk) {
                bf16x8 af[4], bfr[4];
                #pragma unroll
                for (int i = 0; i < 4; ++i) {
                    const int r = wm + i * 16 + lr;
                    const int phys = ((kk * 4 + quad) ^ rmod) * 16;
                    af[i] = *(const bf16x8*)(asmb + r * 128 + phys);
                }
                #pragma unroll
                for (int j = 0; j < 4; ++j) {
                    const int r = wn + j * 16 + lr;
                    const int phys = ((kk * 4 + quad) ^ rmod) * 16;
                    bfr[j] = *(const bf16x8*)(bsmb + r * 128 + phys);
                }
                #pragma unroll
                for (int i = 0; i < 4; ++i)
                    #pragma unroll
                    for (int j = 0; j < 4; ++j)
                        acc[i][j] = __builtin_amdgcn_mfma_f32_16x16x32_bf16(af[i], bfr[j], acc[i][j], 0, 0, 0);
            }
            __syncthreads();
        }
    }

    #pragma unroll
    for (int j = 0; j < 4; ++j) {
        const int pg    = pix0 + wn + j * 16 + lr;
        const int ni    = pg / PLANE;
        const int inner = pg - ni * PLANE;
        float* op = out + (size_t)ni * (COUT * PLANE) + inner;
        #pragma unroll
        for (int i = 0; i < 4; ++i) {
            const int crow = c0 + wm + i * 16 + quad * 4;
            #pragma unroll
            for (int r = 0; r < 4; ++r)
                op[(size_t)(crow + r) * PLANE] = acc[i][j][r] + bias[crow + r];
        }
    }
}

extern "C" void kernel_launch(void* const* d_in, const int* in_sizes, int n_in,
                              void* d_out, int out_size, void* d_ws, size_t ws_size,
                              hipStream_t stream) {
    const float* in   = (const float*)d_in[0];
    const float* wt   = (const float*)d_in[1];
    const float* bias = (const float*)d_in[2];
    float* out        = (float*)d_out;

    unsigned short* wb = (unsigned short*)((char*)d_ws + WB_OFF);
    unsigned short* xp = (unsigned short*)((char*)d_ws + XP_OFF);

    wprep<<<COUT, 256, 0, stream>>>(wt, wb);
    xprep<<<NBATCH * HP, 256, 0, stream>>>(in, xp);

    conv_mfma<<<(COUT / BM) * ((NBATCH * PLANE) / BN), 256, 0, stream>>>(wb, xp, bias, out);
}